// Round 1
// baseline (856.461 us; speedup 1.0000x reference)
//
#include <hip/hip_runtime.h>
#include <math.h>

#define N_FILT 32
#define FILT_DIM 101
#define HALF 50
#define WT 380                      // output columns per block (5 * 380 = 1900)
#define XS (WT + FILT_DIM - 1)      // 480 staged x floats per block

// ---------------------------------------------------------------------------
// Kernel 1: generate the 32 SincNet band-pass filters (fp64 math, fp32 out).
// One block per filter, threads 0..100 = taps, LDS tree for the signed max.
// ---------------------------------------------------------------------------
__global__ void gen_filters_kernel(const float* __restrict__ fb1,
                                   const float* __restrict__ fband,
                                   float* __restrict__ filt) {
  __shared__ double red[128];
  const int o = blockIdx.x;
  const int i = threadIdx.x;

  const double fbeg = fabs((double)fb1[o]) + (1.0 / 250.0);
  const double fend = fbeg + fabs((double)fband[o]) + (5.0 / 250.0);

  double v = 0.0;
  if (i < FILT_DIM) {
    const int d = i - HALF;
    if (d == 0) {
      v = 2.0 * (fend - fbeg);  // sinc(0) = 1 for both terms
    } else {
      const double t  = (double)(d < 0 ? -d : d) / 250.0;  // t_right[|d|-1]
      const double ae = 2.0 * M_PI * (fend * 250.0) * t;
      const double ab = 2.0 * M_PI * (fbeg * 250.0) * t;
      v = 2.0 * fend * (sin(ae) / ae) - 2.0 * fbeg * (sin(ab) / ab);
    }
  }

  red[i] = (i < FILT_DIM) ? v : -1e300;
  __syncthreads();
  for (int s = 64; s > 0; s >>= 1) {
    if (i < s) red[i] = fmax(red[i], red[i + s]);
    __syncthreads();
  }
  const double mx = red[0];

  if (i < FILT_DIM) {
    // window: n_i = i * 101/100 ; w = 0.54 - 0.46 cos(2*pi*n/101)
    const double n = (double)i * ((double)FILT_DIM / (double)(FILT_DIM - 1));
    const double w = 0.54 - 0.46 * cos(2.0 * M_PI * n / (double)FILT_DIM);
    filt[o * FILT_DIM + i] = (float)((v / mx) * w);
  }
}

// ---------------------------------------------------------------------------
// Kernel 2: the 1x101 VALID convolution, exploiting filter symmetry:
//   out = sum_{k<50} f[k]*(x[w+k]+x[w+100-k]) + f[50]*x[w+50]
// 50 pair-adds shared across all 32 filters -> 1.87x fewer VALU ops.
// Block = 384 threads, one (n,h) row x 380-wide output tile.
// ---------------------------------------------------------------------------
__global__ __launch_bounds__(384) void sinc_conv_kernel(
    const float* __restrict__ x, const float* __restrict__ filt,
    float* __restrict__ out) {
  __shared__ float xs[XS];
  const int t   = threadIdx.x;
  const int wt  = blockIdx.x;   // 0..4
  const int row = blockIdx.y;   // n*64 + h, 0..2047
  const int w0  = wt * WT;

  const float* xrow = x + (size_t)row * 2000 + w0;
  if (t < XS / 4) {  // 120 float4 loads, 16B-aligned (w0*4 % 16 == 0)
    reinterpret_cast<float4*>(xs)[t] =
        reinterpret_cast<const float4*>(xrow)[t];
  }
  __syncthreads();
  if (t >= WT) return;

  float s[HALF + 1];
#pragma unroll
  for (int k = 0; k < HALF; ++k) s[k] = xs[t + k] + xs[t + 100 - k];
  s[HALF] = xs[t + HALF];

  const int n = row >> 6;
  const int h = row & 63;
  // out[((n*32 + o)*64 + h)*1900 + w] = out[(n*2048 + h)*1900 + w + o*121600]
  const size_t base = ((size_t)n * 2048 + h) * 1900 + (size_t)(w0 + t);

#pragma unroll 2
  for (int o = 0; o < N_FILT; ++o) {
    const float* __restrict__ f = filt + o * FILT_DIM;  // wave-uniform -> s_load
    float acc = 0.f;
#pragma unroll
    for (int k = 0; k <= HALF; ++k) acc = fmaf(f[k], s[k], acc);
    out[base + (size_t)o * 121600] = acc;
  }
}

// ---------------------------------------------------------------------------
extern "C" void kernel_launch(void* const* d_in, const int* in_sizes, int n_in,
                              void* d_out, int out_size, void* d_ws, size_t ws_size,
                              hipStream_t stream) {
  const float* x     = (const float*)d_in[0];
  const float* fb1   = (const float*)d_in[1];
  const float* fband = (const float*)d_in[2];
  float* out  = (float*)d_out;
  float* filt = (float*)d_ws;  // 32*101 floats, regenerated every launch

  gen_filters_kernel<<<dim3(N_FILT), 128, 0, stream>>>(fb1, fband, filt);
  sinc_conv_kernel<<<dim3(5, 2048), 384, 0, stream>>>(x, filt, out);
}